// Round 1
// baseline (1047.496 us; speedup 1.0000x reference)
//
#include <hip/hip_runtime.h>

// ---------------------------------------------------------------------------
// GraphTrajSimEncoder on MI355X.
// Pipeline (all on `stream`, graph-capture safe):
//   1. Per edge set: indegree counts (int atomics) -> dinv = rsqrt(deg+1)
//   2. CSR build (counts -> scan -> fill with per-edge norms), reused by both layers
//   3. xc = bf16(concat(x, d2an)) padded to K=384; W's converted/concat to bf16
//   4. xa = xc @ Wnode1^T, xb = xc @ Wnode2^T        (MFMA bf16 GEMM)
//   5. For each (layer, set): CSR gather-aggregate (a1|a2) -> GEMM with [W1|W2]
//      h   = 0.5*relu(.) + 0.5*relu(.)   (bf16)
//      out = 0.5*relu(.) + 0.5*relu(.)   (f32, into d_out)
// ---------------------------------------------------------------------------

using bf16x8  = __attribute__((ext_vector_type(8))) __bf16;
using floatx4 = __attribute__((ext_vector_type(4))) float;

__device__ __forceinline__ float b2f(unsigned short b) {
    return __uint_as_float(((unsigned)b) << 16);
}
__device__ __forceinline__ unsigned short f2b(float f) {
    unsigned u = __float_as_uint(f);
    return (unsigned short)((u + 0x7FFFu + ((u >> 16) & 1u)) >> 16);
}

// ---------------- small utility kernels ----------------

__global__ void k_cnt(const int* __restrict__ col, int E, int* __restrict__ cnt) {
    int e = blockIdx.x * 256 + threadIdx.x;
    if (e < E) atomicAdd(&cnt[col[e]], 1);
}

__global__ void k_dinv(const int* __restrict__ cnt, float* __restrict__ dinv, int n) {
    int i = blockIdx.x * 256 + threadIdx.x;
    if (i < n) dinv[i] = rsqrtf((float)(cnt[i] + 1));   // +1 self loop; always > 0
}

__global__ void k_copy(const int* __restrict__ a, int* __restrict__ b, int n) {
    int i = blockIdx.x * 256 + threadIdx.x;
    if (i < n) b[i] = a[i];
}

// single-block scan: off[0]=0, off[i+1]=sum(cnt[0..i])
__global__ __launch_bounds__(1024) void k_scan(const int* __restrict__ cnt,
                                               int* __restrict__ off, int n) {
    __shared__ int wsum[16];
    __shared__ int wpre[16];
    __shared__ int carry;
    const int t = threadIdx.x;
    const int lane = t & 63;
    const int w = t >> 6;
    if (t == 0) { carry = 0; off[0] = 0; }
    __syncthreads();
    for (int base = 0; base < n; base += 1024) {
        int i = base + t;
        int v = (i < n) ? cnt[i] : 0;
        #pragma unroll
        for (int d = 1; d < 64; d <<= 1) {
            int u = __shfl_up(v, d, 64);
            if (lane >= d) v += u;
        }
        if (lane == 63) wsum[w] = v;
        __syncthreads();
        if (t < 16) {
            int s = wsum[t];
            #pragma unroll
            for (int d = 1; d < 16; d <<= 1) {
                int u = __shfl_up(s, d, 16);
                if (t >= d) s += u;
            }
            wpre[t] = s;
        }
        __syncthreads();
        int add = carry + (w > 0 ? wpre[w - 1] : 0);
        if (i < n) off[i + 1] = v + add;
        __syncthreads();
        if (t == 0) carry += wpre[15];
        __syncthreads();
    }
}

__global__ void k_fill(const int* __restrict__ row, const int* __restrict__ col,
                       const float* __restrict__ attr, int E,
                       const float* __restrict__ dinv, int* __restrict__ cur,
                       int* __restrict__ src, float* __restrict__ w1,
                       float* __restrict__ w2) {
    int e = blockIdx.x * 256 + threadIdx.x;
    if (e >= E) return;
    int r = row[e], c = col[e];
    int p = atomicAdd(&cur[c], 1);
    src[p] = r;
    w1[p] = dinv[r] * dinv[c];
    float a = attr[e];
    w2[p] = (a > 0.0f) ? fminf(rsqrtf(a), 1.0f) : 0.0f;
}

// xc[i][k] (bf16, K padded to KP): k<F -> x, k<KC -> d2an, else 0
__global__ void k_xc(const float* __restrict__ x, const float* __restrict__ pe,
                     unsigned short* __restrict__ xc, int n, int F, int PEd,
                     int KC, int KP) {
    int idx = blockIdx.x * 256 + threadIdx.x;
    if (idx >= n * KP) return;
    int i = idx / KP, k = idx - i * KP;
    float v = 0.0f;
    if (k < F)        v = x[(size_t)i * F + k];
    else if (k < KC)  v = pe[(size_t)i * PEd + (k - F)];
    xc[idx] = f2b(v);
}

// W [F][KC] f32 -> Wc [F][KP] bf16, zero-padded
__global__ void k_wn(const float* __restrict__ W, unsigned short* __restrict__ Wc,
                     int F, int KC, int KP) {
    int idx = blockIdx.x * 256 + threadIdx.x;
    if (idx >= F * KP) return;
    int o = idx / KP, k = idx - o * KP;
    Wc[idx] = f2b(k < KC ? W[(size_t)o * KC + k] : 0.0f);
}

// Wcat [F][512] bf16 = [Wa | Wb] along K (each [F][256] f32)
__global__ void k_wcat(const float* __restrict__ Wa, const float* __restrict__ Wb,
                       unsigned short* __restrict__ Wc, int F) {
    int idx = blockIdx.x * 256 + threadIdx.x;
    if (idx >= F * 512) return;
    int o = idx >> 9, k = idx & 511;
    float v = (k < 256) ? Wa[(size_t)o * 256 + k] : Wb[(size_t)o * 256 + (k - 256)];
    Wc[idx] = f2b(v);
}

// ---------------- CSR gather-aggregation ----------------
// One wave per node, 4 features/lane. A12[i] = [a1(256) | a2(256)] bf16.
__global__ __launch_bounds__(256) void k_agg(
    const unsigned short* __restrict__ X,      // [n][256] bf16
    const int* __restrict__ off, const int* __restrict__ src,
    const float* __restrict__ w1, const float* __restrict__ w2,
    const float* __restrict__ dinv,
    unsigned short* __restrict__ A12, int n) {
    int gw = (blockIdx.x * 256 + threadIdx.x) >> 6;
    int lane = threadIdx.x & 63;
    if (gw >= n) return;

    ushort4 xi = ((const ushort4*)(X + (size_t)gw * 256))[lane];
    float di = dinv[gw];
    float ws = di * di;
    float v0 = b2f(xi.x), v1 = b2f(xi.y), v2 = b2f(xi.z), v3 = b2f(xi.w);
    float a10 = ws * v0, a11 = ws * v1, a12v = ws * v2, a13 = ws * v3;  // self loop, deg_norm
    float a20 = v0, a21 = v1, a22 = v2, a23 = v3;                        // self loop, edge_norm=1

    int e = off[gw], e1 = off[gw + 1];
    for (; e + 1 < e1; e += 2) {
        int ja = src[e], jb = src[e + 1];
        float wa1 = w1[e], wa2 = w2[e];
        float wb1 = w1[e + 1], wb2 = w2[e + 1];
        ushort4 xa = ((const ushort4*)(X + (size_t)ja * 256))[lane];
        ushort4 xb = ((const ushort4*)(X + (size_t)jb * 256))[lane];
        float f0 = b2f(xa.x), f1 = b2f(xa.y), f2 = b2f(xa.z), f3 = b2f(xa.w);
        a10 += wa1 * f0; a11 += wa1 * f1; a12v += wa1 * f2; a13 += wa1 * f3;
        a20 += wa2 * f0; a21 += wa2 * f1; a22  += wa2 * f2; a23 += wa2 * f3;
        float g0 = b2f(xb.x), g1 = b2f(xb.y), g2 = b2f(xb.z), g3 = b2f(xb.w);
        a10 += wb1 * g0; a11 += wb1 * g1; a12v += wb1 * g2; a13 += wb1 * g3;
        a20 += wb2 * g0; a21 += wb2 * g1; a22  += wb2 * g2; a23 += wb2 * g3;
    }
    if (e < e1) {
        int j = src[e];
        float wa1 = w1[e], wa2 = w2[e];
        ushort4 xj = ((const ushort4*)(X + (size_t)j * 256))[lane];
        float f0 = b2f(xj.x), f1 = b2f(xj.y), f2 = b2f(xj.z), f3 = b2f(xj.w);
        a10 += wa1 * f0; a11 += wa1 * f1; a12v += wa1 * f2; a13 += wa1 * f3;
        a20 += wa2 * f0; a21 += wa2 * f1; a22  += wa2 * f2; a23 += wa2 * f3;
    }

    ushort4 o1, o2;
    o1.x = f2b(a10); o1.y = f2b(a11); o1.z = f2b(a12v); o1.w = f2b(a13);
    o2.x = f2b(a20); o2.y = f2b(a21); o2.z = f2b(a22);  o2.w = f2b(a23);
    ((ushort4*)(A12 + (size_t)gw * 512))[lane] = o1;
    ((ushort4*)(A12 + (size_t)gw * 512 + 256))[lane] = o2;
}

// ---------------- bf16 MFMA GEMM (B^T layout) ----------------
// C[M][Nc] = op(A[M][K] @ B[Nc][K]^T). 128x128 tile, BK=32, 4 waves (2x2 of 64x64),
// global_load_lds width-16 staging (m97 structure).
#define GLL(g, l) \
    __builtin_amdgcn_global_load_lds((__attribute__((address_space(1))) void*)(g), \
                                     (__attribute__((address_space(3))) void*)(l), 16, 0, 0)

__global__ __launch_bounds__(256) void gemm_bt(
    const unsigned short* __restrict__ A, const unsigned short* __restrict__ B,
    int M, int K, int Nc,
    float* __restrict__ outF, unsigned short* __restrict__ outH,
    float alpha, int relu, int accum) {
    __shared__ __align__(16) unsigned short sA[128 * 32];
    __shared__ __align__(16) unsigned short sB[128 * 32];
    const int tid = threadIdx.x;
    const int lane = tid & 63;
    const int wave = tid >> 6;
    const int bm = blockIdx.x * 128;
    const int bn = blockIdx.y * 128;

    // staging: wave w covers tile rows [w*32, w*32+32), 2 instrs of 16 rows each,
    // 4 lanes per row, 16B (8 bf16) per lane
    const int r0 = wave * 32 + (lane >> 2);
    const int kcol = (lane & 3) * 8;
    const int ga0 = min(bm + r0, M - 1);
    const int ga1 = min(bm + r0 + 16, M - 1);
    const int gb0 = min(bn + r0, Nc - 1);
    const int gb1 = min(bn + r0 + 16, Nc - 1);
    const unsigned short* pa0 = A + (size_t)ga0 * K + kcol;
    const unsigned short* pa1 = A + (size_t)ga1 * K + kcol;
    const unsigned short* pb0 = B + (size_t)gb0 * K + kcol;
    const unsigned short* pb1 = B + (size_t)gb1 * K + kcol;
    unsigned short* la0 = &sA[wave * 1024];
    unsigned short* la1 = &sA[wave * 1024 + 512];
    unsigned short* lb0 = &sB[wave * 1024];
    unsigned short* lb1 = &sB[wave * 1024 + 512];

    floatx4 acc[4][4];
    #pragma unroll
    for (int i = 0; i < 4; i++)
        #pragma unroll
        for (int j = 0; j < 4; j++) acc[i][j] = (floatx4){0.f, 0.f, 0.f, 0.f};

    const int mbase = (wave & 1) * 64 + (lane & 15);
    const int nbase = (wave >> 1) * 64 + (lane & 15);
    const int koff = (lane >> 4) * 8;

    for (int kk = 0; kk < K; kk += 32) {
        GLL(pa0 + kk, la0);
        GLL(pa1 + kk, la1);
        GLL(pb0 + kk, lb0);
        GLL(pb1 + kk, lb1);
        __syncthreads();   // drains vmcnt -> LDS tile visible
        bf16x8 af[4], bf[4];
        #pragma unroll
        for (int mi = 0; mi < 4; mi++)
            af[mi] = *(const bf16x8*)&sA[(mbase + mi * 16) * 32 + koff];
        #pragma unroll
        for (int ni = 0; ni < 4; ni++)
            bf[ni] = *(const bf16x8*)&sB[(nbase + ni * 16) * 32 + koff];
        #pragma unroll
        for (int mi = 0; mi < 4; mi++)
            #pragma unroll
            for (int ni = 0; ni < 4; ni++)
                acc[mi][ni] = __builtin_amdgcn_mfma_f32_16x16x32_bf16(
                    af[mi], bf[ni], acc[mi][ni], 0, 0, 0);
        __syncthreads();   // tile consumed before next overwrite
    }

    // epilogue: C/D layout col=lane&15, row=(lane>>4)*4+reg  [m89-verified]
    const int crow = bm + (wave & 1) * 64 + (lane >> 4) * 4;
    const int ccol = bn + (wave >> 1) * 64 + (lane & 15);
    #pragma unroll
    for (int mi = 0; mi < 4; mi++) {
        #pragma unroll
        for (int ni = 0; ni < 4; ni++) {
            #pragma unroll
            for (int r = 0; r < 4; r++) {
                int row = crow + mi * 16 + r;
                if (row >= M) continue;
                int col = ccol + ni * 16;
                float v = acc[mi][ni][r];
                if (relu) v = fmaxf(v, 0.0f);
                v *= alpha;
                size_t idx = (size_t)row * Nc + col;
                if (outF) {
                    outF[idx] = accum ? (outF[idx] + v) : v;
                } else {
                    float p = accum ? b2f(outH[idx]) : 0.0f;
                    outH[idx] = f2b(p + v);
                }
            }
        }
    }
}

// ---------------- host orchestration ----------------

extern "C" void kernel_launch(void* const* d_in, const int* in_sizes, int n_in,
                              void* d_out, int out_size, void* d_ws, size_t ws_size,
                              hipStream_t stream) {
    const int F = 256;
    const int N = in_sizes[0] / F;
    const int PEd = in_sizes[1] / N;          // 98
    const int E = in_sizes[2] / 2;            // 800000
    const int KC = F + PEd;                   // 354
    const int KP = (KC + 31) & ~31;           // 384

    const float* x   = (const float*)d_in[0];
    const float* pe  = (const float*)d_in[1];
    const int*   ei0 = (const int*)d_in[2];
    const float* ea0 = (const float*)d_in[3];
    const int*   ei1 = (const int*)d_in[4];
    const float* ea1 = (const float*)d_in[5];
    const float* Wn1 = (const float*)d_in[6];
    const float* Wn2 = (const float*)d_in[7];
    const float* W11 = (const float*)d_in[8];
    const float* W12 = (const float*)d_in[9];
    const float* W21 = (const float*)d_in[10];
    const float* W22 = (const float*)d_in[11];
    const float* W31 = (const float*)d_in[12];
    const float* W32 = (const float*)d_in[13];
    const float* W41 = (const float*)d_in[14];
    const float* W42 = (const float*)d_in[15];
    float* out = (float*)d_out;

    char* p = (char*)d_ws;
    auto alloc = [&](size_t b) -> char* {
        char* r = p;
        p += (b + 255) & ~(size_t)255;
        return r;
    };
    int*   cnt0  = (int*)alloc((size_t)N * 4);
    int*   cnt1  = (int*)alloc((size_t)N * 4);
    int*   off0  = (int*)alloc((size_t)(N + 1) * 4);
    int*   off1  = (int*)alloc((size_t)(N + 1) * 4);
    int*   cur0  = (int*)alloc((size_t)N * 4);
    int*   cur1  = (int*)alloc((size_t)N * 4);
    float* dinv0 = (float*)alloc((size_t)N * 4);
    float* dinv1 = (float*)alloc((size_t)N * 4);
    int*   src0  = (int*)alloc((size_t)E * 4);
    int*   src1  = (int*)alloc((size_t)E * 4);
    float* w10   = (float*)alloc((size_t)E * 4);
    float* w20   = (float*)alloc((size_t)E * 4);
    float* w1b   = (float*)alloc((size_t)E * 4);
    float* w2b   = (float*)alloc((size_t)E * 4);
    unsigned short* wn0c = (unsigned short*)alloc((size_t)F * KP * 2);
    unsigned short* wn1c = (unsigned short*)alloc((size_t)F * KP * 2);
    unsigned short* wc0  = (unsigned short*)alloc((size_t)F * 512 * 2);
    unsigned short* wc1  = (unsigned short*)alloc((size_t)F * 512 * 2);
    unsigned short* wc2  = (unsigned short*)alloc((size_t)F * 512 * 2);
    unsigned short* wc3  = (unsigned short*)alloc((size_t)F * 512 * 2);
    unsigned short* xa   = (unsigned short*)alloc((size_t)N * F * 2);
    unsigned short* xb   = (unsigned short*)alloc((size_t)N * F * 2);
    unsigned short* h    = (unsigned short*)alloc((size_t)N * F * 2);
    // a12 overlays xc (xc dead after both node-transform GEMMs; 512 >= KP)
    unsigned short* a12  = (unsigned short*)alloc((size_t)N * 512 * 2);
    unsigned short* xc   = a12;

    const int B = 256;
    const int gE = (E + B - 1) / B;
    const int gN = (N + B - 1) / B;
    dim3 gemm_grid((N + 127) / 128, 2);

    // 1. degree / dinv / CSR
    hipMemsetAsync(cnt0, 0, (size_t)N * 4, stream);
    hipMemsetAsync(cnt1, 0, (size_t)N * 4, stream);
    k_cnt<<<gE, B, 0, stream>>>(ei0 + E, E, cnt0);
    k_cnt<<<gE, B, 0, stream>>>(ei1 + E, E, cnt1);
    k_dinv<<<gN, B, 0, stream>>>(cnt0, dinv0, N);
    k_dinv<<<gN, B, 0, stream>>>(cnt1, dinv1, N);
    k_scan<<<1, 1024, 0, stream>>>(cnt0, off0, N);
    k_scan<<<1, 1024, 0, stream>>>(cnt1, off1, N);
    k_copy<<<gN, B, 0, stream>>>(off0, cur0, N);
    k_copy<<<gN, B, 0, stream>>>(off1, cur1, N);
    k_fill<<<gE, B, 0, stream>>>(ei0, ei0 + E, ea0, E, dinv0, cur0, src0, w10, w20);
    k_fill<<<gE, B, 0, stream>>>(ei1, ei1 + E, ea1, E, dinv1, cur1, src1, w1b, w2b);

    // 2. bf16 conversions
    k_xc<<<((size_t)N * KP + B - 1) / B, B, 0, stream>>>(x, pe, xc, N, F, PEd, KC, KP);
    k_wn<<<(F * KP + B - 1) / B, B, 0, stream>>>(Wn1, wn0c, F, KC, KP);
    k_wn<<<(F * KP + B - 1) / B, B, 0, stream>>>(Wn2, wn1c, F, KC, KP);
    k_wcat<<<(F * 512 + B - 1) / B, B, 0, stream>>>(W11, W12, wc0, F);
    k_wcat<<<(F * 512 + B - 1) / B, B, 0, stream>>>(W21, W22, wc1, F);
    k_wcat<<<(F * 512 + B - 1) / B, B, 0, stream>>>(W31, W32, wc2, F);
    k_wcat<<<(F * 512 + B - 1) / B, B, 0, stream>>>(W41, W42, wc3, F);

    // 3. node transforms (first layer PE path)
    gemm_bt<<<gemm_grid, B, 0, stream>>>(xc, wn0c, N, KP, F, nullptr, xa, 1.0f, 0, 0);
    gemm_bt<<<gemm_grid, B, 0, stream>>>(xc, wn1c, N, KP, F, nullptr, xb, 1.0f, 0, 0);

    // 4. layer 1: h = 0.5*relu(conv1(xa)) + 0.5*relu(conv2(xb))
    const int gAgg = ((size_t)N * 64 + B - 1) / B;
    k_agg<<<gAgg, B, 0, stream>>>(xa, off0, src0, w10, w20, dinv0, a12, N);
    gemm_bt<<<gemm_grid, B, 0, stream>>>(a12, wc0, N, 512, F, nullptr, h, 0.5f, 1, 0);
    k_agg<<<gAgg, B, 0, stream>>>(xb, off1, src1, w1b, w2b, dinv1, a12, N);
    gemm_bt<<<gemm_grid, B, 0, stream>>>(a12, wc1, N, 512, F, nullptr, h, 0.5f, 1, 1);

    // 5. layer 2: out = 0.5*relu(conv3(h)) + 0.5*relu(conv4(h))  (f32)
    k_agg<<<gAgg, B, 0, stream>>>(h, off0, src0, w10, w20, dinv0, a12, N);
    gemm_bt<<<gemm_grid, B, 0, stream>>>(a12, wc2, N, 512, F, out, nullptr, 0.5f, 1, 0);
    k_agg<<<gAgg, B, 0, stream>>>(h, off1, src1, w1b, w2b, dinv1, a12, N);
    gemm_bt<<<gemm_grid, B, 0, stream>>>(a12, wc3, N, 512, F, out, nullptr, 0.5f, 1, 1);
}

// Round 2
// 918.680 us; speedup vs baseline: 1.1402x; 1.1402x over previous
//
#include <hip/hip_runtime.h>

// ---------------------------------------------------------------------------
// GraphTrajSimEncoder on MI355X — round 2.
// R1 post-mortem: k_fill scattered-write bound (106 MB WRITE_SIZE for 9.6 MB
// payload; 3 scattered 4B streams). Fix: single 4B record (src:u16, w2:fp16),
// w1 recomputed in k_agg from dinv (L2-resident). Fused per-set kernels via
// blockIdx.y, weight conversions into one kernel, node-transform GEMMs via
// blockIdx.z, layer-2 aggs fused (2nd output overlays dead xa|xb).
// ---------------------------------------------------------------------------

using bf16x8  = __attribute__((ext_vector_type(8))) __bf16;
using floatx4 = __attribute__((ext_vector_type(4))) float;

__device__ __forceinline__ float b2f(unsigned short b) {
    return __uint_as_float(((unsigned)b) << 16);
}
__device__ __forceinline__ unsigned short f2b(float f) {
    unsigned u = __float_as_uint(f);
    return (unsigned short)((u + 0x7FFFu + ((u >> 16) & 1u)) >> 16);
}
__device__ __forceinline__ unsigned short f2h(float f) {
    _Float16 h = (_Float16)f;
    return __builtin_bit_cast(unsigned short, h);
}
__device__ __forceinline__ float h2f(unsigned short u) {
    return (float)__builtin_bit_cast(_Float16, u);
}

// ---------------- graph preprocessing ----------------

__global__ void k_cnt2(const int* __restrict__ col0, const int* __restrict__ col1,
                       int E, int* __restrict__ cnt0, int* __restrict__ cnt1) {
    int e = blockIdx.x * 256 + threadIdx.x;
    const int* col = blockIdx.y ? col1 : col0;
    int* cnt = blockIdx.y ? cnt1 : cnt0;
    if (e < E) atomicAdd(&cnt[col[e]], 1);
}

// grid (1,2): one block scans one set. off[0]=0, off[i+1]=sum(cnt[0..i])
__global__ __launch_bounds__(1024) void k_scan2(
    const int* __restrict__ cnt0, const int* __restrict__ cnt1,
    int* __restrict__ off0, int* __restrict__ off1, int n) {
    const int* cnt = blockIdx.y ? cnt1 : cnt0;
    int* off = blockIdx.y ? off1 : off0;
    __shared__ int wsum[16];
    __shared__ int wpre[16];
    __shared__ int carry;
    const int t = threadIdx.x;
    const int lane = t & 63;
    const int w = t >> 6;
    if (t == 0) { carry = 0; off[0] = 0; }
    __syncthreads();
    for (int base = 0; base < n; base += 1024) {
        int i = base + t;
        int v = (i < n) ? cnt[i] : 0;
        #pragma unroll
        for (int d = 1; d < 64; d <<= 1) {
            int u = __shfl_up(v, d, 64);
            if (lane >= d) v += u;
        }
        if (lane == 63) wsum[w] = v;
        __syncthreads();
        if (t < 16) {
            int s = wsum[t];
            #pragma unroll
            for (int d = 1; d < 16; d <<= 1) {
                int u = __shfl_up(s, d, 16);
                if (t >= d) s += u;
            }
            wpre[t] = s;
        }
        __syncthreads();
        int add = carry + (w > 0 ? wpre[w - 1] : 0);
        if (i < n) off[i + 1] = v + add;
        __syncthreads();
        if (t == 0) carry += wpre[15];
        __syncthreads();
    }
}

// dinv = rsqrt(deg+1) (self loop), cur = off  — grid (gN,2)
__global__ void k_prep(const int* __restrict__ cnt0, const int* __restrict__ cnt1,
                       const int* __restrict__ off0, const int* __restrict__ off1,
                       float* __restrict__ dinv0, float* __restrict__ dinv1,
                       int* __restrict__ cur0, int* __restrict__ cur1, int n) {
    int i = blockIdx.x * 256 + threadIdx.x;
    if (i >= n) return;
    const int* cnt = blockIdx.y ? cnt1 : cnt0;
    const int* off = blockIdx.y ? off1 : off0;
    float* dinv = blockIdx.y ? dinv1 : dinv0;
    int* cur = blockIdx.y ? cur1 : cur0;
    dinv[i] = rsqrtf((float)(cnt[i] + 1));
    cur[i] = off[i];
}

// CSR fill: single 4B record per edge = (src:u16 | fp16(w2) << 16).
// w1 = dinv[src]*dinv[dst] is recomputed in k_agg (not stored).
__global__ void k_fill2(const int* __restrict__ ei0, const float* __restrict__ ea0,
                        const int* __restrict__ ei1, const float* __restrict__ ea1,
                        int E, int* __restrict__ cur0, int* __restrict__ cur1,
                        unsigned* __restrict__ rec0, unsigned* __restrict__ rec1) {
    int e = blockIdx.x * 256 + threadIdx.x;
    if (e >= E) return;
    const int* ei = blockIdx.y ? ei1 : ei0;
    const float* ea = blockIdx.y ? ea1 : ea0;
    int* cur = blockIdx.y ? cur1 : cur0;
    unsigned* rec = blockIdx.y ? rec1 : rec0;
    int r = ei[e];          // source (row)
    int c = ei[E + e];      // target (col)
    float a = ea[e];
    float w2 = (a > 0.0f) ? fminf(rsqrtf(a), 1.0f) : 0.0f;
    int p = atomicAdd(&cur[c], 1);
    rec[p] = (unsigned)r | ((unsigned)f2h(w2) << 16);   // requires N < 65536
}

// ---------------- dtype conversions ----------------

// xc[i][k] (bf16, K padded to KP): k<F -> x, k<KC -> d2an, else 0
__global__ void k_xc(const float* __restrict__ x, const float* __restrict__ pe,
                     unsigned short* __restrict__ xc, int n, int F, int PEd,
                     int KC, int KP) {
    int idx = blockIdx.x * 256 + threadIdx.x;
    if (idx >= n * KP) return;
    int i = idx / KP, k = idx - i * KP;
    float v = 0.0f;
    if (k < F)        v = x[(size_t)i * F + k];
    else if (k < KC)  v = pe[(size_t)i * PEd + (k - F)];
    xc[idx] = f2b(v);
}

// all weight conversions in one dispatch:
//   seg 0/1: Wn [F][KC] f32 -> [F][KP] bf16 zero-padded
//   seg 2..5: [Wa|Wb] pairs -> [F][512] bf16
__global__ void k_wall(const float* __restrict__ Wn1, const float* __restrict__ Wn2,
                       const float* __restrict__ W11, const float* __restrict__ W12,
                       const float* __restrict__ W21, const float* __restrict__ W22,
                       const float* __restrict__ W31, const float* __restrict__ W32,
                       const float* __restrict__ W41, const float* __restrict__ W42,
                       unsigned short* __restrict__ wn0c, unsigned short* __restrict__ wn1c,
                       unsigned short* __restrict__ wc0, unsigned short* __restrict__ wc1,
                       unsigned short* __restrict__ wc2, unsigned short* __restrict__ wc3,
                       int F, int KC, int KP) {
    int idx = blockIdx.x * 256 + threadIdx.x;
    int npad = F * KP;
    if (idx < 2 * npad) {
        const float* W = (idx < npad) ? Wn1 : Wn2;
        unsigned short* Wc = (idx < npad) ? wn0c : wn1c;
        int t = (idx < npad) ? idx : idx - npad;
        int o = t / KP, k = t - o * KP;
        Wc[t] = f2b(k < KC ? W[(size_t)o * KC + k] : 0.0f);
        return;
    }
    int t = idx - 2 * npad;
    int seg = F * 512;
    if (t >= 4 * seg) return;
    int which = t / seg;
    int r = t - which * seg;
    const float* Wa = (which == 0) ? W11 : (which == 1) ? W21 : (which == 2) ? W31 : W41;
    const float* Wb = (which == 0) ? W12 : (which == 1) ? W22 : (which == 2) ? W32 : W42;
    unsigned short* Wc = (which == 0) ? wc0 : (which == 1) ? wc1 : (which == 2) ? wc2 : wc3;
    int o = r >> 9, k = r & 511;
    float v = (k < 256) ? Wa[(size_t)o * 256 + k] : Wb[(size_t)o * 256 + (k - 256)];
    Wc[r] = f2b(v);
}

// ---------------- CSR gather-aggregation ----------------
// One wave per node, 4 features/lane. A[i] = [a1(256) | a2(256)] bf16.
// grid (gAgg, nsets): blockIdx.y selects (X, off, rec, dinv, out).
__global__ __launch_bounds__(256) void k_agg(
    const unsigned short* __restrict__ X0, const unsigned short* __restrict__ X1,
    const int* __restrict__ off0, const int* __restrict__ off1,
    const unsigned* __restrict__ rec0, const unsigned* __restrict__ rec1,
    const float* __restrict__ dinv0, const float* __restrict__ dinv1,
    unsigned short* __restrict__ A0, unsigned short* __restrict__ A1, int n) {
    const int s = blockIdx.y;
    const unsigned short* X = s ? X1 : X0;
    const int* off = s ? off1 : off0;
    const unsigned* rec = s ? rec1 : rec0;
    const float* dinv = s ? dinv1 : dinv0;
    unsigned short* A = s ? A1 : A0;

    int gw = (blockIdx.x * 256 + threadIdx.x) >> 6;
    int lane = threadIdx.x & 63;
    if (gw >= n) return;

    ushort4 xi = ((const ushort4*)(X + (size_t)gw * 256))[lane];
    float di = dinv[gw];
    float ws = di * di;
    float v0 = b2f(xi.x), v1 = b2f(xi.y), v2 = b2f(xi.z), v3 = b2f(xi.w);
    float a10 = ws * v0, a11 = ws * v1, a12v = ws * v2, a13 = ws * v3;  // self loop, deg_norm
    float a20 = v0, a21 = v1, a22 = v2, a23 = v3;                        // self loop, edge_norm=1

    int e = off[gw], e1 = off[gw + 1];
    for (; e + 1 < e1; e += 2) {
        unsigned ra = rec[e], rb = rec[e + 1];
        int ja = ra & 0xFFFF, jb = rb & 0xFFFF;
        float wa2 = h2f((unsigned short)(ra >> 16));
        float wb2 = h2f((unsigned short)(rb >> 16));
        float wa1 = dinv[ja] * di;
        float wb1 = dinv[jb] * di;
        ushort4 xa = ((const ushort4*)(X + (size_t)ja * 256))[lane];
        ushort4 xb = ((const ushort4*)(X + (size_t)jb * 256))[lane];
        float f0 = b2f(xa.x), f1 = b2f(xa.y), f2 = b2f(xa.z), f3 = b2f(xa.w);
        a10 += wa1 * f0; a11 += wa1 * f1; a12v += wa1 * f2; a13 += wa1 * f3;
        a20 += wa2 * f0; a21 += wa2 * f1; a22  += wa2 * f2; a23 += wa2 * f3;
        float g0 = b2f(xb.x), g1 = b2f(xb.y), g2 = b2f(xb.z), g3 = b2f(xb.w);
        a10 += wb1 * g0; a11 += wb1 * g1; a12v += wb1 * g2; a13 += wb1 * g3;
        a20 += wb2 * g0; a21 += wb2 * g1; a22  += wb2 * g2; a23 += wb2 * g3;
    }
    if (e < e1) {
        unsigned ra = rec[e];
        int j = ra & 0xFFFF;
        float wa2 = h2f((unsigned short)(ra >> 16));
        float wa1 = dinv[j] * di;
        ushort4 xj = ((const ushort4*)(X + (size_t)j * 256))[lane];
        float f0 = b2f(xj.x), f1 = b2f(xj.y), f2 = b2f(xj.z), f3 = b2f(xj.w);
        a10 += wa1 * f0; a11 += wa1 * f1; a12v += wa1 * f2; a13 += wa1 * f3;
        a20 += wa2 * f0; a21 += wa2 * f1; a22  += wa2 * f2; a23 += wa2 * f3;
    }

    ushort4 o1, o2;
    o1.x = f2b(a10); o1.y = f2b(a11); o1.z = f2b(a12v); o1.w = f2b(a13);
    o2.x = f2b(a20); o2.y = f2b(a21); o2.z = f2b(a22);  o2.w = f2b(a23);
    ((ushort4*)(A + (size_t)gw * 512))[lane] = o1;
    ((ushort4*)(A + (size_t)gw * 512 + 256))[lane] = o2;
}

// ---------------- bf16 MFMA GEMM (B^T layout) ----------------
// C[M][Nc] = op(A[M][K] @ B[Nc][K]^T). 128x128 tile, BK=32, 4 waves (2x2 of 64x64),
// global_load_lds width-16 staging (m97 structure). blockIdx.z selects (B,outH)
// for fused independent GEMMs sharing A.
#define GLL(g, l) \
    __builtin_amdgcn_global_load_lds((__attribute__((address_space(1))) void*)(g), \
                                     (__attribute__((address_space(3))) void*)(l), 16, 0, 0)

__global__ __launch_bounds__(256) void gemm_bt(
    const unsigned short* __restrict__ A,
    const unsigned short* __restrict__ B0, const unsigned short* __restrict__ B1,
    int M, int K, int Nc,
    float* __restrict__ outF,
    unsigned short* __restrict__ outH0, unsigned short* __restrict__ outH1,
    float alpha, int relu, int accum) {
    const unsigned short* B = blockIdx.z ? B1 : B0;
    unsigned short* outH = blockIdx.z ? outH1 : outH0;

    __shared__ __align__(16) unsigned short sA[128 * 32];
    __shared__ __align__(16) unsigned short sB[128 * 32];
    const int tid = threadIdx.x;
    const int lane = tid & 63;
    const int wave = tid >> 6;
    const int bm = blockIdx.x * 128;
    const int bn = blockIdx.y * 128;

    const int r0 = wave * 32 + (lane >> 2);
    const int kcol = (lane & 3) * 8;
    const int ga0 = min(bm + r0, M - 1);
    const int ga1 = min(bm + r0 + 16, M - 1);
    const int gb0 = min(bn + r0, Nc - 1);
    const int gb1 = min(bn + r0 + 16, Nc - 1);
    const unsigned short* pa0 = A + (size_t)ga0 * K + kcol;
    const unsigned short* pa1 = A + (size_t)ga1 * K + kcol;
    const unsigned short* pb0 = B + (size_t)gb0 * K + kcol;
    const unsigned short* pb1 = B + (size_t)gb1 * K + kcol;
    unsigned short* la0 = &sA[wave * 1024];
    unsigned short* la1 = &sA[wave * 1024 + 512];
    unsigned short* lb0 = &sB[wave * 1024];
    unsigned short* lb1 = &sB[wave * 1024 + 512];

    floatx4 acc[4][4];
    #pragma unroll
    for (int i = 0; i < 4; i++)
        #pragma unroll
        for (int j = 0; j < 4; j++) acc[i][j] = (floatx4){0.f, 0.f, 0.f, 0.f};

    const int mbase = (wave & 1) * 64 + (lane & 15);
    const int nbase = (wave >> 1) * 64 + (lane & 15);
    const int koff = (lane >> 4) * 8;

    for (int kk = 0; kk < K; kk += 32) {
        GLL(pa0 + kk, la0);
        GLL(pa1 + kk, la1);
        GLL(pb0 + kk, lb0);
        GLL(pb1 + kk, lb1);
        __syncthreads();
        bf16x8 af[4], bf[4];
        #pragma unroll
        for (int mi = 0; mi < 4; mi++)
            af[mi] = *(const bf16x8*)&sA[(mbase + mi * 16) * 32 + koff];
        #pragma unroll
        for (int ni = 0; ni < 4; ni++)
            bf[ni] = *(const bf16x8*)&sB[(nbase + ni * 16) * 32 + koff];
        #pragma unroll
        for (int mi = 0; mi < 4; mi++)
            #pragma unroll
            for (int ni = 0; ni < 4; ni++)
                acc[mi][ni] = __builtin_amdgcn_mfma_f32_16x16x32_bf16(
                    af[mi], bf[ni], acc[mi][ni], 0, 0, 0);
        __syncthreads();
    }

    // epilogue: C/D layout col=lane&15, row=(lane>>4)*4+reg  [m89-verified]
    const int crow = bm + (wave & 1) * 64 + (lane >> 4) * 4;
    const int ccol = bn + (wave >> 1) * 64 + (lane & 15);
    #pragma unroll
    for (int mi = 0; mi < 4; mi++) {
        #pragma unroll
        for (int ni = 0; ni < 4; ni++) {
            #pragma unroll
            for (int r = 0; r < 4; r++) {
                int row = crow + mi * 16 + r;
                if (row >= M) continue;
                int col = ccol + ni * 16;
                float v = acc[mi][ni][r];
                if (relu) v = fmaxf(v, 0.0f);
                v *= alpha;
                size_t idx = (size_t)row * Nc + col;
                if (outF) {
                    outF[idx] = accum ? (outF[idx] + v) : v;
                } else {
                    float p = accum ? b2f(outH[idx]) : 0.0f;
                    outH[idx] = f2b(p + v);
                }
            }
        }
    }
}

// ---------------- host orchestration ----------------

extern "C" void kernel_launch(void* const* d_in, const int* in_sizes, int n_in,
                              void* d_out, int out_size, void* d_ws, size_t ws_size,
                              hipStream_t stream) {
    const int F = 256;
    const int N = in_sizes[0] / F;
    const int PEd = in_sizes[1] / N;          // 98
    const int E = in_sizes[2] / 2;            // 800000
    const int KC = F + PEd;                   // 354
    const int KP = (KC + 31) & ~31;           // 384

    const float* x   = (const float*)d_in[0];
    const float* pe  = (const float*)d_in[1];
    const int*   ei0 = (const int*)d_in[2];
    const float* ea0 = (const float*)d_in[3];
    const int*   ei1 = (const int*)d_in[4];
    const float* ea1 = (const float*)d_in[5];
    const float* Wn1 = (const float*)d_in[6];
    const float* Wn2 = (const float*)d_in[7];
    const float* W11 = (const float*)d_in[8];
    const float* W12 = (const float*)d_in[9];
    const float* W21 = (const float*)d_in[10];
    const float* W22 = (const float*)d_in[11];
    const float* W31 = (const float*)d_in[12];
    const float* W32 = (const float*)d_in[13];
    const float* W41 = (const float*)d_in[14];
    const float* W42 = (const float*)d_in[15];
    float* out = (float*)d_out;

    char* p = (char*)d_ws;
    auto alloc = [&](size_t b) -> char* {
        char* r = p;
        p += (b + 255) & ~(size_t)255;
        return r;
    };
    int*   cnt0  = (int*)alloc((size_t)N * 4);
    int*   cnt1  = (int*)alloc((size_t)N * 4);
    int*   off0  = (int*)alloc((size_t)(N + 1) * 4);
    int*   off1  = (int*)alloc((size_t)(N + 1) * 4);
    int*   cur0  = (int*)alloc((size_t)N * 4);
    int*   cur1  = (int*)alloc((size_t)N * 4);
    float* dinv0 = (float*)alloc((size_t)N * 4);
    float* dinv1 = (float*)alloc((size_t)N * 4);
    unsigned* rec0 = (unsigned*)alloc((size_t)E * 4);
    unsigned* rec1 = (unsigned*)alloc((size_t)E * 4);
    unsigned short* wn0c = (unsigned short*)alloc((size_t)F * KP * 2);
    unsigned short* wn1c = (unsigned short*)alloc((size_t)F * KP * 2);
    unsigned short* wc0  = (unsigned short*)alloc((size_t)F * 512 * 2);
    unsigned short* wc1  = (unsigned short*)alloc((size_t)F * 512 * 2);
    unsigned short* wc2  = (unsigned short*)alloc((size_t)F * 512 * 2);
    unsigned short* wc3  = (unsigned short*)alloc((size_t)F * 512 * 2);
    // xa and xb allocated CONTIGUOUSLY: their union (N*512 bf16) is reused as
    // the second aggregation buffer in layer 2 (xa/xb dead by then).
    unsigned short* xa   = (unsigned short*)alloc((size_t)N * 512 * 2);
    unsigned short* xb   = xa + (size_t)N * 256;
    unsigned short* h    = (unsigned short*)alloc((size_t)N * F * 2);
    unsigned short* a12  = (unsigned short*)alloc((size_t)N * 512 * 2);  // overlays-free
    unsigned short* xc   = a12;                 // xc dead after node transforms
    unsigned short* a12b = xa;                  // layer-2 second agg output

    const int B = 256;
    const int gE = (E + B - 1) / B;
    const int gN = (N + B - 1) / B;
    const int gAgg = ((size_t)N * 64 + B - 1) / B;
    dim3 gemm_grid((N + 127) / 128, 2);
    dim3 gemm_grid2((N + 127) / 128, 2, 2);

    // 1. degree / dinv / CSR  (both sets per dispatch via blockIdx.y)
    hipMemsetAsync(cnt0, 0, (size_t)N * 4, stream);
    hipMemsetAsync(cnt1, 0, (size_t)N * 4, stream);
    k_cnt2<<<dim3(gE, 2), B, 0, stream>>>(ei0 + E, ei1 + E, E, cnt0, cnt1);
    k_scan2<<<dim3(1, 2), 1024, 0, stream>>>(cnt0, cnt1, off0, off1, N);
    k_prep<<<dim3(gN, 2), B, 0, stream>>>(cnt0, cnt1, off0, off1, dinv0, dinv1, cur0, cur1, N);
    k_fill2<<<dim3(gE, 2), B, 0, stream>>>(ei0, ea0, ei1, ea1, E, cur0, cur1, rec0, rec1);

    // 2. bf16 conversions
    k_xc<<<((size_t)N * KP + B - 1) / B, B, 0, stream>>>(x, pe, xc, N, F, PEd, KC, KP);
    {
        int tot = 2 * F * KP + 4 * F * 512;
        k_wall<<<(tot + B - 1) / B, B, 0, stream>>>(Wn1, Wn2, W11, W12, W21, W22,
                                                    W31, W32, W41, W42,
                                                    wn0c, wn1c, wc0, wc1, wc2, wc3,
                                                    F, KC, KP);
    }

    // 3. node transforms (both in one dispatch via blockIdx.z)
    gemm_bt<<<gemm_grid2, B, 0, stream>>>(xc, wn0c, wn1c, N, KP, F,
                                          nullptr, xa, xb, 1.0f, 0, 0);

    // 4. layer 1: h = 0.5*relu(conv1(agg0(xa))) + 0.5*relu(conv2(agg1(xb)))
    k_agg<<<dim3(gAgg, 1), B, 0, stream>>>(xa, xa, off0, off0, rec0, rec0,
                                           dinv0, dinv0, a12, a12, N);
    gemm_bt<<<gemm_grid, B, 0, stream>>>(a12, wc0, wc0, N, 512, F,
                                         nullptr, h, h, 0.5f, 1, 0);
    k_agg<<<dim3(gAgg, 1), B, 0, stream>>>(xb, xb, off1, off1, rec1, rec1,
                                           dinv1, dinv1, a12, a12, N);
    gemm_bt<<<gemm_grid, B, 0, stream>>>(a12, wc1, wc1, N, 512, F,
                                         nullptr, h, h, 0.5f, 1, 1);

    // 5. layer 2: both aggs in one dispatch (a12b overlays dead xa|xb)
    k_agg<<<dim3(gAgg, 2), B, 0, stream>>>(h, h, off0, off1, rec0, rec1,
                                           dinv0, dinv1, a12, a12b, N);
    gemm_bt<<<gemm_grid, B, 0, stream>>>(a12, wc2, wc2, N, 512, F,
                                         out, nullptr, nullptr, 0.5f, 1, 0);
    gemm_bt<<<gemm_grid, B, 0, stream>>>(a12b, wc3, wc3, N, 512, F,
                                         out, nullptr, nullptr, 0.5f, 1, 1);
}